// Round 4
// baseline (101.133 us; speedup 1.0000x reference)
//
#include <hip/hip_runtime.h>
#include <math.h>

#define N_TOK 512
#define DIM   128
#define KDIM  1024
#define EPSF  1e-14f

// ============ Kernel 1: projection partial GEMM (K-split 8) ============
// grid 256 = ng(16 groups of 32 rows) x cs(2 matrices) x ks(8 k-slices)
// block 512. Per thread: 2 rows x 4 cols, float4 W loads, b128 h reads.
__global__ __launch_bounds__(512) void proj_part(
    const float* __restrict__ token, const float* __restrict__ Wmu,
    const float* __restrict__ Wsg, float* __restrict__ part)
{
    __shared__ float hs[32][128];     // 16 KB: 32 rows x 128-k slice, relu'd
    const int bid = blockIdx.x;
    const int ng = bid >> 4, cs = (bid >> 3) & 1, ks = bid & 7;
    const int t = threadIdx.x;

    #pragma unroll
    for (int rep = 0; rep < 2; ++rep) {
        int f = t + rep * 512;                 // 0..1023 float4 slots
        int row = f >> 5, kq = f & 31;
        float4 v = *(const float4*)(token + (size_t)(ng * 32 + row) * KDIM + ks * 128 + kq * 4);
        v.x = fmaxf(v.x, 0.f); v.y = fmaxf(v.y, 0.f);
        v.z = fmaxf(v.z, 0.f); v.w = fmaxf(v.w, 0.f);
        *(float4*)(&hs[row][kq * 4]) = v;
    }
    __syncthreads();

    const int q = t & 31;          // d-quad (cols q*4..q*4+3)
    const int rsub = t >> 5;       // 0..15 -> rows rsub, rsub+16
    const float* __restrict__ W = (cs ? Wsg : Wmu) + (size_t)(ks * 128) * DIM + q * 4;

    float4 a0 = make_float4(0.f, 0.f, 0.f, 0.f);
    float4 a1 = make_float4(0.f, 0.f, 0.f, 0.f);
    #pragma unroll 2
    for (int k4 = 0; k4 < 32; ++k4) {
        float4 h0 = *(const float4*)(&hs[rsub][k4 * 4]);        // broadcast b128
        float4 h1 = *(const float4*)(&hs[rsub + 16][k4 * 4]);
        const float* wp = W + (size_t)(k4 * 4) * DIM;
        float4 w0 = *(const float4*)(wp);
        float4 w1 = *(const float4*)(wp + DIM);
        float4 w2 = *(const float4*)(wp + 2 * DIM);
        float4 w3 = *(const float4*)(wp + 3 * DIM);
        a0.x = fmaf(h0.x, w0.x, a0.x); a0.y = fmaf(h0.x, w0.y, a0.y);
        a0.z = fmaf(h0.x, w0.z, a0.z); a0.w = fmaf(h0.x, w0.w, a0.w);
        a0.x = fmaf(h0.y, w1.x, a0.x); a0.y = fmaf(h0.y, w1.y, a0.y);
        a0.z = fmaf(h0.y, w1.z, a0.z); a0.w = fmaf(h0.y, w1.w, a0.w);
        a0.x = fmaf(h0.z, w2.x, a0.x); a0.y = fmaf(h0.z, w2.y, a0.y);
        a0.z = fmaf(h0.z, w2.z, a0.z); a0.w = fmaf(h0.z, w2.w, a0.w);
        a0.x = fmaf(h0.w, w3.x, a0.x); a0.y = fmaf(h0.w, w3.y, a0.y);
        a0.z = fmaf(h0.w, w3.z, a0.z); a0.w = fmaf(h0.w, w3.w, a0.w);
        a1.x = fmaf(h1.x, w0.x, a1.x); a1.y = fmaf(h1.x, w0.y, a1.y);
        a1.z = fmaf(h1.x, w0.z, a1.z); a1.w = fmaf(h1.x, w0.w, a1.w);
        a1.x = fmaf(h1.y, w1.x, a1.x); a1.y = fmaf(h1.y, w1.y, a1.y);
        a1.z = fmaf(h1.y, w1.z, a1.z); a1.w = fmaf(h1.y, w1.w, a1.w);
        a1.x = fmaf(h1.z, w2.x, a1.x); a1.y = fmaf(h1.z, w2.y, a1.y);
        a1.z = fmaf(h1.z, w2.z, a1.z); a1.w = fmaf(h1.z, w2.w, a1.w);
        a1.x = fmaf(h1.w, w3.x, a1.x); a1.y = fmaf(h1.w, w3.y, a1.y);
        a1.z = fmaf(h1.w, w3.z, a1.z); a1.w = fmaf(h1.w, w3.w, a1.w);
    }
    const int r0 = ng * 32 + rsub;
    float* dst = part + ((size_t)ks * N_TOK + r0) * 256 + cs * 128 + q * 4;
    *(float4*)dst = a0;
    *(float4*)(dst + 16 * 256) = a1;
}

// ============ Kernel 2: finish projection (row-major only) ============
// grid 64 (8 rows each), block 256. Sums K-split partials, adds bias,
// applies ELU; writes row-major mu/sg/iv.
__global__ __launch_bounds__(256) void proj_finish(
    const float* __restrict__ part, const float* __restrict__ bmu,
    const float* __restrict__ bsg,
    float* __restrict__ mu, float* __restrict__ sg, float* __restrict__ iv)
{
    const int rg = blockIdx.x;
    const int t = threadIdx.x;
    const int q = t & 31, r = t >> 5;      // q: d-quad (0..31), r: row (0..7)
    const int row = rg * 8 + r;
    const int d = q * 4;

    float4 sm = make_float4(0.f, 0.f, 0.f, 0.f);
    float4 ss = make_float4(0.f, 0.f, 0.f, 0.f);
    #pragma unroll
    for (int ks = 0; ks < 8; ++ks) {
        const float* base = part + ((size_t)ks * N_TOK + row) * 256;
        float4 v0 = *(const float4*)(base + d);
        float4 v1 = *(const float4*)(base + 128 + d);
        sm.x += v0.x; sm.y += v0.y; sm.z += v0.z; sm.w += v0.w;
        ss.x += v1.x; ss.y += v1.y; ss.z += v1.z; ss.w += v1.w;
    }
    {
        float4 b = *(const float4*)(bmu + d);
        sm.x += b.x; sm.y += b.y; sm.z += b.z; sm.w += b.w;
    }
    float4 e, vv;
    {
        float4 b = *(const float4*)(bsg + d);
        float x0 = ss.x + b.x, x1 = ss.y + b.y, x2 = ss.z + b.z, x3 = ss.w + b.w;
        e.x = (x0 > 0.f ? x0 : expm1f(x0)) + 1.0f + EPSF;
        e.y = (x1 > 0.f ? x1 : expm1f(x1)) + 1.0f + EPSF;
        e.z = (x2 > 0.f ? x2 : expm1f(x2)) + 1.0f + EPSF;
        e.w = (x3 > 0.f ? x3 : expm1f(x3)) + 1.0f + EPSF;
        vv.x = 1.0f / e.x; vv.y = 1.0f / e.y; vv.z = 1.0f / e.z; vv.w = 1.0f / e.w;
    }
    *(float4*)(mu + (size_t)row * DIM + d) = sm;
    *(float4*)(sg + (size_t)row * DIM + d) = e;
    *(float4*)(iv + (size_t)row * DIM + d) = vv;
}

// ============ Kernel 3: pairwise sym-KL + masked row partial sums ==========
// grid 512 = ig(32 groups of 16 i-rows) x jg(16 groups of 32 j); block 256.
// thread: jl = t&31 (its j), isub = t>>5 -> i-rows {2*isub, 2*isub+1}.
// j-side: LDS, transposed-on-stage sj[3][128][33] (pad -> 4-way write,
// conflict-free read). i-side: direct global b128 broadcast (L1-resident).
// e_ij = exp(D - 0.5*acc), acc = sum_d [(s_j+dm^2)*v_i + (s_i+dm^2)*v_j].
__global__ __launch_bounds__(256) void pair_kernel(
    const float* __restrict__ mu, const float* __restrict__ sg,
    const float* __restrict__ iv, const int* __restrict__ labels,
    const int* __restrict__ mask, float* __restrict__ gpart)
{
    __shared__ float sj[3][DIM][33];       // 49.6 KB
    __shared__ int slab[16], svalid[16];
    const int ig = blockIdx.x >> 4, jg = blockIdx.x & 15;
    const int i0 = ig * 16, j0 = jg * 32;
    const int t = threadIdx.x;

    // stage j-slice (32 rows) transposed: read row-major coalesced,
    // scatter to [d][row] (33-pad -> 4-way bank on writes, free on reads)
    {
        float* sjf = &sj[0][0][0];
        #pragma unroll
        for (int rep = 0; rep < 4; ++rep) {
            int rem = t + rep * 256;           // 0..1023
            int row = rem >> 5, dq = rem & 31;
            size_t src = (size_t)(j0 + row) * DIM + dq * 4;
            int b = (dq * 4) * 33 + row;
            float4 v;
            v = *(const float4*)(mu + src);
            sjf[b] = v.x; sjf[b + 33] = v.y; sjf[b + 66] = v.z; sjf[b + 99] = v.w;
            v = *(const float4*)(sg + src);
            sjf[4224 + b] = v.x; sjf[4224 + b + 33] = v.y;
            sjf[4224 + b + 66] = v.z; sjf[4224 + b + 99] = v.w;
            v = *(const float4*)(iv + src);
            sjf[8448 + b] = v.x; sjf[8448 + b + 33] = v.y;
            sjf[8448 + b + 66] = v.z; sjf[8448 + b + 99] = v.w;
        }
    }
    if (t < 16) {
        int lab = labels[i0 + t];
        slab[t] = lab;
        svalid[t] = (mask[i0 + t] == 1 && lab > 0) ? 1 : 0;
    }
    __syncthreads();

    const int jl = t & 31, isub = t >> 5;
    const int ia = 2 * isub;               // even row; odd row = ia+1
    const int j = j0 + jl;
    const int labj = labels[j];
    const bool validj = (mask[j] == 1) && (labj > 0);

    const float* pm = mu + (size_t)(i0 + ia) * DIM;   // row ia; row ib at +DIM
    const float* ps = sg + (size_t)(i0 + ia) * DIM;
    const float* pv = iv + (size_t)(i0 + ia) * DIM;

    float accA = 0.f, accB = 0.f;
    float mnA = 1e30f, mnB = 1e30f;

    #pragma unroll 4
    for (int q = 0; q < 32; ++q) {
        const int d0 = q * 4;
        float jm0 = sj[0][d0 + 0][jl], jm1 = sj[0][d0 + 1][jl];
        float jm2 = sj[0][d0 + 2][jl], jm3 = sj[0][d0 + 3][jl];
        float js0 = sj[1][d0 + 0][jl], js1 = sj[1][d0 + 1][jl];
        float js2 = sj[1][d0 + 2][jl], js3 = sj[1][d0 + 3][jl];
        float jv0 = sj[2][d0 + 0][jl], jv1 = sj[2][d0 + 1][jl];
        float jv2 = sj[2][d0 + 2][jl], jv3 = sj[2][d0 + 3][jl];

        float4 mA = *(const float4*)(pm + d0);
        float4 sA = *(const float4*)(ps + d0);
        float4 vA = *(const float4*)(pv + d0);
        float4 mB = *(const float4*)(pm + DIM + d0);
        float4 sB = *(const float4*)(ps + DIM + d0);
        float4 vB = *(const float4*)(pv + DIM + d0);

        float dm;
        dm = mA.x - jm0; accA = fmaf(fmaf(dm, dm, js0), vA.x, fmaf(fmaf(dm, dm, sA.x), jv0, accA)); mnA = fminf(mnA, fabsf(dm));
        dm = mA.y - jm1; accA = fmaf(fmaf(dm, dm, js1), vA.y, fmaf(fmaf(dm, dm, sA.y), jv1, accA)); mnA = fminf(mnA, fabsf(dm));
        dm = mA.z - jm2; accA = fmaf(fmaf(dm, dm, js2), vA.z, fmaf(fmaf(dm, dm, sA.z), jv2, accA)); mnA = fminf(mnA, fabsf(dm));
        dm = mA.w - jm3; accA = fmaf(fmaf(dm, dm, js3), vA.w, fmaf(fmaf(dm, dm, sA.w), jv3, accA)); mnA = fminf(mnA, fabsf(dm));

        dm = mB.x - jm0; accB = fmaf(fmaf(dm, dm, js0), vB.x, fmaf(fmaf(dm, dm, sB.x), jv0, accB)); mnB = fminf(mnB, fabsf(dm));
        dm = mB.y - jm1; accB = fmaf(fmaf(dm, dm, js1), vB.y, fmaf(fmaf(dm, dm, sB.y), jv1, accB)); mnB = fminf(mnB, fabsf(dm));
        dm = mB.z - jm2; accB = fmaf(fmaf(dm, dm, js2), vB.z, fmaf(fmaf(dm, dm, sB.z), jv2, accB)); mnB = fminf(mnB, fabsf(dm));
        dm = mB.w - jm3; accB = fmaf(fmaf(dm, dm, js3), vB.w, fmaf(fmaf(dm, dm, sB.w), jv3, accB)); mnB = fminf(mnB, fabsf(dm));
    }

    const int ib = ia + 1;
    float eA = expf(128.0f - 0.5f * accA);
    float eB = expf(128.0f - 0.5f * accB);
    bool pvA = validj && (svalid[ia] != 0) && (mnA != 0.0f);
    bool pvB = validj && (svalid[ib] != 0) && (mnB != 0.0f);
    bool smA = pvA && (labj == slab[ia]);
    bool smB = pvB && (labj == slab[ib]);
    float dA = pvA ? eA : 0.f, nA = smA ? eA : 0.f, cA = smA ? 1.f : 0.f;
    float dB = pvB ? eB : 0.f, nB = smB ? eB : 0.f, cB = smB ? 1.f : 0.f;

    // reduce over the 32 j-lanes (masks < 32 stay within half-wave)
    #pragma unroll
    for (int m = 1; m < 32; m <<= 1) {
        cA += __shfl_xor(cA, m); nA += __shfl_xor(nA, m); dA += __shfl_xor(dA, m);
        cB += __shfl_xor(cB, m); nB += __shfl_xor(nB, m); dB += __shfl_xor(dB, m);
    }
    if (jl == 0) {
        float* pa = gpart + ((size_t)jg * N_TOK + i0 + ia) * 3;
        float* pb = gpart + ((size_t)jg * N_TOK + i0 + ib) * 3;
        pa[0] = cA; pa[1] = nA; pa[2] = dA;
        pb[0] = cB; pb[1] = nB; pb[2] = dB;
    }
}

// ============ Kernel 4: final loss ============
__global__ __launch_bounds__(512) void final_kernel(
    const float* __restrict__ gpart, float* __restrict__ out)
{
    __shared__ float redL[8], redI[8];
    const int t = threadIdx.x;           // 512 threads = 512 rows
    float c = 0.f, nm = 0.f, dn = 0.f;
    #pragma unroll
    for (int jg = 0; jg < 16; ++jg) {
        const float* p = gpart + ((size_t)jg * N_TOK + t) * 3;
        c += p[0]; nm += p[1]; dn += p[2];
    }
    const bool inc = c > 0.5f;
    float lf = inc ? (-logf(nm) + logf(dn) + logf(c)) : 0.f;
    float fi = inc ? 1.f : 0.f;
    #pragma unroll
    for (int m = 1; m < 64; m <<= 1) {
        lf += __shfl_xor(lf, m);
        fi += __shfl_xor(fi, m);
    }
    if ((t & 63) == 0) { redL[t >> 6] = lf; redI[t >> 6] = fi; }
    __syncthreads();
    if (t == 0) {
        float L = 0.f, I = 0.f;
        #pragma unroll
        for (int w = 0; w < 8; ++w) { L += redL[w]; I += redI[w]; }
        out[0] = L / fmaxf(I, 1.0f);
    }
}

// ============ launcher ============
extern "C" void kernel_launch(void* const* d_in, const int* in_sizes, int n_in,
                              void* d_out, int out_size, void* d_ws, size_t ws_size,
                              hipStream_t stream) {
    const float* token  = (const float*)d_in[0];
    const int*   labels = (const int*)d_in[1];
    const int*   mask   = (const int*)d_in[2];
    const float* Wmu    = (const float*)d_in[3];
    const float* bmu    = (const float*)d_in[4];
    const float* Wsg    = (const float*)d_in[5];
    const float* bsg    = (const float*)d_in[6];

    float* ws = (float*)d_ws;
    float* part  = ws;                        // 8*512*256 = 1,048,576 floats
    float* mu    = part + 1048576;            // 65,536
    float* sg    = mu + 65536;
    float* iv    = sg + 65536;
    float* gpart = iv + 65536;                // 16*512*3 = 24,576 floats

    proj_part<<<256, 512, 0, stream>>>(token, Wmu, Wsg, part);
    proj_finish<<<64, 256, 0, stream>>>(part, bmu, bsg, mu, sg, iv);
    pair_kernel<<<512, 256, 0, stream>>>(mu, sg, iv, labels, mask, gpart);
    final_kernel<<<1, 512, 0, stream>>>(gpart, (float*)d_out);
}